// Round 14
// baseline (1799.731 us; speedup 1.0000x reference)
//
#include <hip/hip_runtime.h>
#include <math.h>

#define BATCH 16
#define T 512
#define NT 6
#define START 4
#define STOP 5
#define NEGV -10000.0f
#define LOG2E 1.4426950408889634f
#define NBLK 16  // lstm blocks; block k owns gate cols {n*256 + k*16 + c}

typedef __attribute__((ext_vector_type(8))) short short8;
typedef __attribute__((ext_vector_type(4))) float f32x4;
typedef __attribute__((ext_vector_type(4))) int i32x4;

__device__ __forceinline__ float fast_sig(float x) {
    float e = __builtin_amdgcn_exp2f(-LOG2E * x);
    return __builtin_amdgcn_rcpf(1.f + e);
}
__device__ __forceinline__ float fast_tanh(float x) {
    float e = __builtin_amdgcn_exp2f(-2.f * LOG2E * x);
    return (1.f - e) * __builtin_amdgcn_rcpf(1.f + e);
}
__device__ __forceinline__ unsigned bf16_rne(float f) {
    unsigned u = __builtin_bit_cast(unsigned, f);
    u += 0x7FFFu + ((u >> 16) & 1u);
    return u >> 16;
}
__device__ __forceinline__ float bf_lo(unsigned v) {
    return __builtin_bit_cast(float, (v & 0xffffu) << 16);
}
__device__ __forceinline__ float bf_hi(unsigned v) {
    return __builtin_bit_cast(float, v & 0xffff0000u);
}
// LDS-only barrier: does NOT drain vmcnt -> prefetches/publishes stay in flight.
__device__ __forceinline__ void bar_lds() {
    asm volatile("s_waitcnt lgkmcnt(0)" ::: "memory");
    __builtin_amdgcn_sched_barrier(0);
    __builtin_amdgcn_s_barrier();
}

// ws layout (byte offsets) — NO aliasing anywhere:
//   [0, 16MB)            Xpb bf16 [t][k][n][lane][j] (32KB/step page)
//   [16MB, 17MB)         WihT fp32 (dead after input_proj)
//   [17MB, 17.5MB)       Wf bf16 MFMA B-fragments
//   [17.5MB, +192KB)     feats fp32 [b][t][6]
//   [18MB, 26MB)         Hg u64[512][16][16][8]: unit = {2 bf16 h | tag<<32}, tag of page
//                        t = t+1. Zeroed by transpose_wih EVERY call -> no stale tags
//                        across replays, deterministic timing, safe first validation run.

__global__ void transpose_wih(const float* __restrict__ W_ih, float* __restrict__ WihT,
                              unsigned long long* __restrict__ Hg) {
    int o = blockIdx.x * blockDim.x + threadIdx.x;
    if (o >= 256 * 1024) return;
    unsigned long long* hz = Hg + (size_t)o * 4;
    hz[0] = 0; hz[1] = 0; hz[2] = 0; hz[3] = 0;   // 262144 threads x 4 = 1M u64 = 8MB
    int k = o >> 10;
    int g = o & 1023;
    WihT[o] = W_ih[g * 256 + k];
}

// Pack W_hh (fp32 [1024][256]) into bf16 MFMA B-fragments (r6 layout, proven).
// flat frag f = ((k*4+n)*8+kt); lane l: g = n*256 + k*16 + (l&15), kk = kt*32 + (l>>4)*8 + j
__global__ void wf_prep(const float* __restrict__ W_hh, unsigned short* __restrict__ Wf) {
    int t = blockIdx.x * 256 + threadIdx.x;  // 0..32767
    int l = t & 63, kt = (t >> 6) & 7, n = (t >> 9) & 3, w = t >> 11;
    int g = n * 256 + w * 16 + (l & 15);
    int kk = kt * 32 + (l >> 4) * 8;
    const float* src = W_hh + g * 256 + kk;
    unsigned short* dst = Wf + (size_t)t * 8;
#pragma unroll
    for (int j = 0; j < 8; j++) dst[j] = (unsigned short)bf16_rne(src[j]);
}

// One block = 16 (b,t) rows, 1024 threads = 1 per gate. Writes Xpb (bf16) in MFMA C-layout.
__global__ __launch_bounds__(1024) void input_proj(const int* __restrict__ sentence,
                                                   const float* __restrict__ embedding,
                                                   const float* __restrict__ WihT,
                                                   const float* __restrict__ b_ih,
                                                   const float* __restrict__ b_hh,
                                                   unsigned short* __restrict__ Xpb) {
    __shared__ __align__(16) float emb[16][260];
    int tid = threadIdx.x;
    int bt0 = blockIdx.x * 16;
    {
        int r = tid >> 6, j = tid & 63;
        int row = sentence[bt0 + r];
        const float4* src = (const float4*)(embedding + (size_t)row * 256);
        float4 v = src[j];
        float* dst = &emb[r][j * 4];
        dst[0] = v.x; dst[1] = v.y; dst[2] = v.z; dst[3] = v.w;
    }
    __syncthreads();
    int g = tid;
    float bias = b_ih[g] + b_hh[g];
    float acc[16];
#pragma unroll
    for (int r = 0; r < 16; r++) acc[r] = bias;
    const float* wp = WihT + g;
    for (int k4 = 0; k4 < 64; k4++) {
        float w0 = wp[(k4 * 4 + 0) * 1024];
        float w1 = wp[(k4 * 4 + 1) * 1024];
        float w2 = wp[(k4 * 4 + 2) * 1024];
        float w3 = wp[(k4 * 4 + 3) * 1024];
#pragma unroll
        for (int r = 0; r < 16; r++) {
            float4 e = *(const float4*)&emb[r][k4 * 4];
            acc[r] += w0 * e.x + w1 * e.y + w2 * e.z + w3 * e.w;
        }
    }
    int b = bt0 >> 9, t0 = bt0 & 511;
    int q = b >> 2, j = b & 3;
    int n = g >> 8, u = g & 255, k = u >> 4, cc = u & 15;
    int lane = q * 16 + cc;
#pragma unroll
    for (int r = 0; r < 16; r++) {
        int t = t0 + r;
        Xpb[(size_t)(((t * 16 + k) * 4 + n) * 64 + lane) * 4 + j] =
            (unsigned short)bf16_rne(acc[r]);
    }
}

// 16 blocks x 256 threads. Block k owns 64 gate cols (wave n = gate type). Exchange via
// self-validating {2h|tag} u64 pages: publish = fire-and-forget (no drain, no flag).
// Per step: 2-stage wait: (1) poll 1 unit/lane covering ALL 16 producers x 4 waves ->
// (2) bulk gather 32 u64 + revalidate (rare retry, s_sleep-paced). One LDS-only barrier.
// Act+publish spread over all 256 threads (shfl-paired) -> no straggler wave.
// Deadlock-free by induction: publish is unconditional; page 0 needs no poll.
__global__ __launch_bounds__(256) void lstm_mfma(const unsigned short* __restrict__ Wf,
                                                 const unsigned short* __restrict__ Xpb,
                                                 unsigned long long* __restrict__ Hg) {
    __shared__ float gl2[2][4][16][16];  // [parity][gate][b][c]
    int tid = threadIdx.x;
    int k = blockIdx.x;
    int n = tid >> 6;          // wave = gate type (i,f,g,o)
    int l = tid & 63;
    int q = l >> 4, c = l & 15;

    // B-fragments: 8 x short8 = 32 VGPR (r6 indexing, proven)
    short8 wr[8];
#pragma unroll
    for (int kt = 0; kt < 8; kt++)
        wr[kt] = *(const short8*)(Wf + ((size_t)((k * 4 + n) * 8 + kt) * 64 + l) * 8);

    // Xp bf16: [t][k][n][lane][j]; this thread's 4 values = 8B; t-stride 16384 ushorts
    const unsigned short* xb = Xpb + ((size_t)(k * 4 + n)) * 256 + (size_t)l * 4;
    uint2 xv = *(const uint2*)xb;

    // gather base (u64): af[kt] = h[row=l&15][cols kt*32+q*8 .. +8) -> block 2kt+(q>>1),
    // up0 = (q&1)*4; page layout [blk][row][up]: idx = blk*128 + row*8 + up
    int gb = (q >> 1) * 128 + (l & 15) * 8 + (q & 1) * 4;
    // poll unit: lane l watches block (l&15), row (l>>4)*4 (one row per producer WAVE), up=1
    int pollu = (l & 15) * 128 + (l >> 4) * 32 + 1;

    // act ownership: thread owns (b_own = tid>>4, col ul = tid&15) -> c_st scalar
    float c_st = 0.f;
    int b_own = tid >> 4, ul = tid & 15;
    int ubase = k * 128 + b_own * 8 + (ul >> 1);  // unit this thread's h lands in
    bool even = (ul & 1) == 0;

    for (int t = 0; t < T; t++) {
        f32x4 acc;
        acc[0] = bf_lo(xv.x); acc[1] = bf_hi(xv.x);
        acc[2] = bf_lo(xv.y); acc[3] = bf_hi(xv.y);

        if (t > 0) {
            const unsigned long long* pg = Hg + (size_t)(t - 1) * 2048;
            // stage 1: cheap poll, one unit per producer-block x wave (4K loads/round)
            while (true) {
                unsigned long long p = __hip_atomic_load(pg + pollu, __ATOMIC_RELAXED,
                                                         __HIP_MEMORY_SCOPE_AGENT);
                if (__all((unsigned)(p >> 32) == (unsigned)t)) break;
            }
            // stage 2: bulk gather 32 u64; revalidate (rarely loops; s_sleep guard)
            unsigned long long vv[8][4];
#pragma unroll
            for (int kt = 0; kt < 8; kt++)
#pragma unroll
                for (int e = 0; e < 4; e++)
                    vv[kt][e] = __hip_atomic_load(pg + kt * 256 + gb + e, __ATOMIC_RELAXED,
                                                  __HIP_MEMORY_SCOPE_AGENT);
            while (true) {
                bool ok = true;
#pragma unroll
                for (int kt = 0; kt < 8; kt++)
#pragma unroll
                    for (int e = 0; e < 4; e++)
                        ok = ok & ((unsigned)(vv[kt][e] >> 32) == (unsigned)t);
                if (__all(ok)) break;
                asm volatile("s_sleep 2");
#pragma unroll
                for (int kt = 0; kt < 8; kt++)
#pragma unroll
                    for (int e = 0; e < 4; e++)
                        vv[kt][e] = __hip_atomic_load(pg + kt * 256 + gb + e, __ATOMIC_RELAXED,
                                                      __HIP_MEMORY_SCOPE_AGENT);
            }
            short8 af[8];
#pragma unroll
            for (int kt = 0; kt < 8; kt++) {
                i32x4 pk = {(int)vv[kt][0], (int)vv[kt][1], (int)vv[kt][2], (int)vv[kt][3]};
                af[kt] = __builtin_bit_cast(short8, pk);
            }
#pragma unroll
            for (int kt = 0; kt < 8; kt++)
                acc = __builtin_amdgcn_mfma_f32_16x16x32_bf16(af[kt], wr[kt], acc, 0, 0, 0);
        }

        // prefetch next Xp (no draining barriers anywhere -> stays in flight)
        uint2 xn = xv;
        if (t + 1 < T) xn = *(const uint2*)(xb + (size_t)(t + 1) * 16384);

        // gate exchange into parity buffer
        {
            float(*gl)[16][16] = gl2[t & 1];
#pragma unroll
            for (int j = 0; j < 4; j++) gl[n][q * 4 + j][c] = acc[j];
        }
        bar_lds();  // gates ready (LDS-only)

        // all-thread act: thread owns (b_own, ul); pair h via shfl; even lanes publish
        {
            const float(*glr)[16][16] = gl2[t & 1];
            float iv = fast_sig(glr[0][b_own][ul]);
            float fg = fast_sig(glr[1][b_own][ul]);
            float gv = fast_tanh(glr[2][b_own][ul]);
            float ov = fast_sig(glr[3][b_own][ul]);
            c_st = fg * c_st + iv * gv;
            unsigned hv = bf16_rne(ov * fast_tanh(c_st));
            unsigned part = (unsigned)__shfl_xor((int)hv, 1);
            if (even) {
                unsigned long long unit = (unsigned long long)(hv | (part << 16)) |
                                          ((unsigned long long)(unsigned)(t + 1) << 32);
                __hip_atomic_store(Hg + (size_t)t * 2048 + ubase, unit,
                                   __ATOMIC_RELAXED, __HIP_MEMORY_SCOPE_AGENT);
            }
            asm volatile("" ::: "memory");  // publish precedes next poll in program order
        }
        xv = xn;
    }
}

// feats[b][t][tag] = h(b,t) . W_out[tag] + b_out[tag].  2048 blocks x 256, wave = one (b,t).
__global__ __launch_bounds__(256) void feats_k(const unsigned long long* __restrict__ Hg,
                                               const float* __restrict__ W_out,
                                               const float* __restrict__ b_out,
                                               float* __restrict__ feats) {
    int wid = blockIdx.x * 4 + (threadIdx.x >> 6);
    int l = threadIdx.x & 63;
    int b = wid >> 9, t = wid & 511;
    // lane l covers cols u = l*4 + {0..3} -> units (l>>2)*128 + b*8 + (l&3)*2 + {0,1}
    const uint4* src =
        (const uint4*)(Hg + (size_t)t * 2048 + (l >> 2) * 128 + b * 8 + (l & 3) * 2);
    uint4 v = *src;
    float h0 = bf_lo(v.x), h1 = bf_hi(v.x), h2 = bf_lo(v.z), h3 = bf_hi(v.z);
    int ub = l * 4;
#pragma unroll
    for (int tag = 0; tag < 6; tag++) {
        float4 wv = *(const float4*)(W_out + tag * 256 + ub);
        float p = h0 * wv.x + h1 * wv.y + h2 * wv.z + h3 * wv.w;
#pragma unroll
        for (int off = 32; off; off >>= 1) p += __shfl_down(p, off);
        if (l == 0) feats[((size_t)b * 512 + t) * 6 + tag] = p + b_out[tag];
    }
}

// 16 blocks x 64 threads. Lane nx owns next-tag nx; fv broadcast via shfl each step.
__global__ __launch_bounds__(64) void crf_scan(const float* __restrict__ feats,
                                               const float* __restrict__ trans,
                                               float* __restrict__ out) {
    __shared__ float fl[T * 6];
    __shared__ unsigned char bp[T * 8];
    int b = blockIdx.x, tid = threadIdx.x;
    const float4* src = (const float4*)(feats + (size_t)b * 3072);
#pragma unroll
    for (int i = 0; i < 12; i++) ((float4*)fl)[tid + i * 64] = src[tid + i * 64];
    int nx = (tid < 6) ? tid : 0;
    float tr0 = trans[nx * 6 + 0], tr1 = trans[nx * 6 + 1], tr2 = trans[nx * 6 + 2],
          tr3 = trans[nx * 6 + 3], tr4 = trans[nx * 6 + 4], tr5 = trans[nx * 6 + 5];
    float fv0 = NEGV, fv1 = NEGV, fv2 = NEGV, fv3 = NEGV, fv4 = 0.f, fv5 = NEGV;  // START=4
    __syncthreads();
    for (int t = 0; t < T; t++) {
        float best = fv0 + tr0; int arg = 0; float s;
        s = fv1 + tr1; if (s > best) { best = s; arg = 1; }
        s = fv2 + tr2; if (s > best) { best = s; arg = 2; }
        s = fv3 + tr3; if (s > best) { best = s; arg = 3; }
        s = fv4 + tr4; if (s > best) { best = s; arg = 4; }
        s = fv5 + tr5; if (s > best) { best = s; arg = 5; }  // strict >: first-max
        float nf = best + fl[t * 6 + nx];
        if (tid < 6) bp[t * 8 + tid] = (unsigned char)arg;
        fv0 = __shfl(nf, 0); fv1 = __shfl(nf, 1); fv2 = __shfl(nf, 2);
        fv3 = __shfl(nf, 3); fv4 = __shfl(nf, 4); fv5 = __shfl(nf, 5);
    }
    __syncthreads();
    if (tid == 0) {
        float best = fv0 + trans[STOP * 6 + 0]; int arg = 0; float s;
        s = fv1 + trans[STOP * 6 + 1]; if (s > best) { best = s; arg = 1; }
        s = fv2 + trans[STOP * 6 + 2]; if (s > best) { best = s; arg = 2; }
        s = fv3 + trans[STOP * 6 + 3]; if (s > best) { best = s; arg = 3; }
        s = fv4 + trans[STOP * 6 + 4]; if (s > best) { best = s; arg = 4; }
        s = fv5 + trans[STOP * 6 + 5]; if (s > best) { best = s; arg = 5; }
        out[b] = best;
        int tag = arg;
        float* paths = out + 16 + (size_t)b * 512;
        for (int t = T - 1; t >= 0; t--) {
            paths[t] = (float)tag;
            tag = bp[t * 8 + tag];
        }
    }
}

extern "C" void kernel_launch(void* const* d_in, const int* in_sizes, int n_in,
                              void* d_out, int out_size, void* d_ws, size_t ws_size,
                              hipStream_t stream) {
    const int* sentence = (const int*)d_in[0];
    const float* embedding = (const float*)d_in[1];
    const float* W_ih = (const float*)d_in[2];
    const float* W_hh = (const float*)d_in[3];
    const float* b_ih = (const float*)d_in[4];
    const float* b_hh = (const float*)d_in[5];
    const float* W_out = (const float*)d_in[6];
    const float* b_out = (const float*)d_in[7];
    const float* trans = (const float*)d_in[8];
    float* out = (float*)d_out;
    char* ws = (char*)d_ws;

    unsigned short* Xpb = (unsigned short*)ws;                       // 16 MB
    float* WihT = (float*)(ws + 16777216);                           // 1 MB
    unsigned short* Wf = (unsigned short*)(ws + 17825792);           // 512 KB
    float* feats = (float*)(ws + 18350080);                          // 192 KB
    unsigned long long* Hg = (unsigned long long*)(ws + 18874368);   // 8 MB, NO alias

    hipLaunchKernelGGL(transpose_wih, dim3(1024), dim3(256), 0, stream, W_ih, WihT, Hg);
    hipLaunchKernelGGL(input_proj, dim3(BATCH * T / 16), dim3(1024), 0, stream,
                       sentence, embedding, WihT, b_ih, b_hh, Xpb);
    hipLaunchKernelGGL(wf_prep, dim3(128), dim3(256), 0, stream, W_hh, Wf);
    hipLaunchKernelGGL(lstm_mfma, dim3(NBLK), dim3(256), 0, stream, Wf, Xpb, Hg);
    hipLaunchKernelGGL(feats_k, dim3(2048), dim3(256), 0, stream, Hg, W_out, b_out, feats);
    hipLaunchKernelGGL(crf_scan, dim3(BATCH), dim3(64), 0, stream, feats, trans, out);
}

// Round 15
// 1069.552 us; speedup vs baseline: 1.6827x; 1.6827x over previous
//
#include <hip/hip_runtime.h>
#include <math.h>

#define BATCH 16
#define T 512
#define NT 6
#define START 4
#define STOP 5
#define NEGV -10000.0f
#define LOG2E 1.4426950408889634f
#define NBLK 16  // lstm blocks; block k owns gate cols {n*256 + k*16 + c} -> units [16k,16k+16)

typedef __attribute__((ext_vector_type(8))) short short8;
typedef __attribute__((ext_vector_type(4))) float f32x4;

union U16B { unsigned long long u[2]; short8 s; };

__device__ __forceinline__ float fast_sig(float x) {
    float e = __builtin_amdgcn_exp2f(-LOG2E * x);
    return __builtin_amdgcn_rcpf(1.f + e);
}
__device__ __forceinline__ float fast_tanh(float x) {
    float e = __builtin_amdgcn_exp2f(-2.f * LOG2E * x);
    return (1.f - e) * __builtin_amdgcn_rcpf(1.f + e);
}
__device__ __forceinline__ unsigned bf16_rne(float f) {
    unsigned u = __builtin_bit_cast(unsigned, f);
    u += 0x7FFFu + ((u >> 16) & 1u);
    return u >> 16;
}
__device__ __forceinline__ float bf_lo(unsigned v) {
    return __builtin_bit_cast(float, (v & 0xffffu) << 16);
}
__device__ __forceinline__ float bf_hi(unsigned v) {
    return __builtin_bit_cast(float, v & 0xffff0000u);
}

// ws layout (byte offsets) — NO aliasing:
//   [0, 16MB)        Xpb bf16 [t][k][n][lane][j] (32KB/step page)
//   [16MB, 17MB)     WihT fp32 (dead after input_proj)
//   [17MB, 17.5MB)   Wf bf16 MFMA B-fragments
//   [17.5MB, +192K)  feats fp32 [b][t][6]
//   [18MB, 22MB)     Hg ushort [t][ks][b][ul] h history (8KB/step page)
//   [23MB, +2KB)     flags int[512] (per-block step flags, 64B stride, zeroed each call)

__global__ void transpose_wih(const float* __restrict__ W_ih, float* __restrict__ WihT,
                              int* __restrict__ flags) {
    int o = blockIdx.x * blockDim.x + threadIdx.x;
    if (o < 512) flags[o] = 0;
    if (o >= 256 * 1024) return;
    int k = o >> 10;
    int g = o & 1023;
    WihT[o] = W_ih[g * 256 + k];
}

// Pack W_hh (fp32 [1024][256]) into bf16 MFMA B-fragments (r6 layout, proven).
// flat frag f = ((k*4+n)*8+kt); lane l: g = n*256 + k*16 + (l&15), kk = kt*32 + (l>>4)*8 + j
__global__ void wf_prep(const float* __restrict__ W_hh, unsigned short* __restrict__ Wf) {
    int t = blockIdx.x * 256 + threadIdx.x;  // 0..32767
    int l = t & 63, kt = (t >> 6) & 7, n = (t >> 9) & 3, w = t >> 11;
    int g = n * 256 + w * 16 + (l & 15);
    int kk = kt * 32 + (l >> 4) * 8;
    const float* src = W_hh + g * 256 + kk;
    unsigned short* dst = Wf + (size_t)t * 8;
#pragma unroll
    for (int j = 0; j < 8; j++) dst[j] = (unsigned short)bf16_rne(src[j]);
}

// One block = 16 (b,t) rows, 1024 threads = 1 per gate. Writes Xpb (bf16) in MFMA C-layout.
__global__ __launch_bounds__(1024) void input_proj(const int* __restrict__ sentence,
                                                   const float* __restrict__ embedding,
                                                   const float* __restrict__ WihT,
                                                   const float* __restrict__ b_ih,
                                                   const float* __restrict__ b_hh,
                                                   unsigned short* __restrict__ Xpb) {
    __shared__ __align__(16) float emb[16][260];
    int tid = threadIdx.x;
    int bt0 = blockIdx.x * 16;
    {
        int r = tid >> 6, j = tid & 63;
        int row = sentence[bt0 + r];
        const float4* src = (const float4*)(embedding + (size_t)row * 256);
        float4 v = src[j];
        float* dst = &emb[r][j * 4];
        dst[0] = v.x; dst[1] = v.y; dst[2] = v.z; dst[3] = v.w;
    }
    __syncthreads();
    int g = tid;
    float bias = b_ih[g] + b_hh[g];
    float acc[16];
#pragma unroll
    for (int r = 0; r < 16; r++) acc[r] = bias;
    const float* wp = WihT + g;
    for (int k4 = 0; k4 < 64; k4++) {
        float w0 = wp[(k4 * 4 + 0) * 1024];
        float w1 = wp[(k4 * 4 + 1) * 1024];
        float w2 = wp[(k4 * 4 + 2) * 1024];
        float w3 = wp[(k4 * 4 + 3) * 1024];
#pragma unroll
        for (int r = 0; r < 16; r++) {
            float4 e = *(const float4*)&emb[r][k4 * 4];
            acc[r] += w0 * e.x + w1 * e.y + w2 * e.z + w3 * e.w;
        }
    }
    int b = bt0 >> 9, t0 = bt0 & 511;
    int q = b >> 2, j = b & 3;
    int n = g >> 8, u = g & 255, k = u >> 4, cc = u & 15;
    int lane = q * 16 + cc;
#pragma unroll
    for (int r = 0; r < 16; r++) {
        int t = t0 + r;
        Xpb[(size_t)(((t * 16 + k) * 4 + n) * 64 + lane) * 4 + j] =
            (unsigned short)bf16_rne(acc[r]);
    }
}

// 16 blocks x 256 threads — r6's PROVEN structure (935us) + 3 local fixes:
// (1) s_sleep-throttled flag spin (cuts LLC contention from 4096 spinners);
// (2) bf16 Xp stream (half the fetch);
// (3) act spread over all 256 threads (1 unit each, scalar c_st, shfl-paired u32 publish).
// Protocol identical: publish (agent atomics) -> __syncthreads drain -> flag; spin; gather.
__global__ __launch_bounds__(256) void lstm_mfma(const unsigned short* __restrict__ Wf,
                                                 const unsigned short* __restrict__ Xpb,
                                                 unsigned short* __restrict__ Hg,
                                                 int* __restrict__ flags) {
    __shared__ float gl[4][16][16];
    int tid = threadIdx.x;
    int k = blockIdx.x;
    int n = tid >> 6;          // wave = gate type (i,f,g,o)
    int l = tid & 63;
    int q = l >> 4;

    // B-fragments of this block's W_hh slice: 8 x short8 = 32 VGPR (r6 verbatim)
    short8 wr[8];
#pragma unroll
    for (int kt = 0; kt < 8; kt++)
        wr[kt] = *(const short8*)(Wf + ((size_t)((k * 4 + n) * 8 + kt) * 64 + l) * 8);

    // Xp bf16: this thread's 4 gates = 8B; t-stride 16384 ushorts
    const unsigned short* xb = Xpb + ((size_t)(k * 4 + n)) * 256 + (size_t)l * 4;
    uint2 xv = *(const uint2*)xb;

    // A-frag base within Hg[t] (ull units) — r6 verbatim
    int abase_us = (q >> 1) * 256 + (l & 15) * 16 + (q & 1) * 8;
    int abase_ull = abase_us >> 2;

    // act ownership: thread owns (b_own = tid>>4, col ul = tid&15); scalar c-state
    float c_st = 0.f;
    int b_own = tid >> 4, ul = tid & 15;

    int* myflag = flags + k * 16;
    int* spinflag = flags + (l & 15) * 16;

    for (int t = 0; t < T; t++) {
        // prefetch next step's Xp at loop top (has the whole step to land before barrier B)
        uint2 xn = xv;
        if (t + 1 < T) xn = *(const uint2*)(xb + (size_t)(t + 1) * 16384);

        f32x4 acc;
        acc[0] = bf_lo(xv.x); acc[1] = bf_hi(xv.x);
        acc[2] = bf_lo(xv.y); acc[3] = bf_hi(xv.y);

        if (t > 0) {
            // throttled spin: lane l watches flags[l&15]; s_sleep 1 between polls
            while (true) {
                int f = __hip_atomic_load(spinflag, __ATOMIC_RELAXED, __HIP_MEMORY_SCOPE_AGENT);
                if (__all(f >= t)) break;
                asm volatile("s_sleep 1");
            }
            __builtin_amdgcn_fence(__ATOMIC_ACQUIRE, "workgroup");  // compiler ordering only
            const unsigned long long* hsrc =
                (const unsigned long long*)(Hg + (size_t)(t - 1) * 4096) + abase_ull;
            short8 af[8];
#pragma unroll
            for (int kt = 0; kt < 8; kt++) {
                U16B cv;
                cv.u[0] = __hip_atomic_load(hsrc + kt * 128 + 0, __ATOMIC_RELAXED,
                                            __HIP_MEMORY_SCOPE_AGENT);
                cv.u[1] = __hip_atomic_load(hsrc + kt * 128 + 1, __ATOMIC_RELAXED,
                                            __HIP_MEMORY_SCOPE_AGENT);
                af[kt] = cv.s;
            }
#pragma unroll
            for (int kt = 0; kt < 8; kt++)
                acc = __builtin_amdgcn_mfma_f32_16x16x32_bf16(af[kt], wr[kt], acc, 0, 0, 0);
        }

        // gate exchange: lane (q,c) reg j -> (b=q*4+j, col c), gate n
        {
            int c = l & 15;
#pragma unroll
            for (int j = 0; j < 4; j++) gl[n][q * 4 + j][c] = acc[j];
        }
        __syncthreads();  // A: gates ready

        // act: all 256 threads, 1 (b,u) each; pair h via shfl; even-ul threads publish u32
        {
            float iv = fast_sig(gl[0][b_own][ul]);
            float fg = fast_sig(gl[1][b_own][ul]);
            float gv = fast_tanh(gl[2][b_own][ul]);
            float ov = fast_sig(gl[3][b_own][ul]);
            c_st = fg * c_st + iv * gv;
            unsigned hv = bf16_rne(ov * fast_tanh(c_st));
            unsigned part = (unsigned)__shfl_xor((int)hv, 1);
            if ((ul & 1) == 0) {
                unsigned word = hv | (part << 16);
                __hip_atomic_store((unsigned*)(Hg + (size_t)t * 4096 + k * 256) +
                                       (b_own * 8 + (ul >> 1)),
                                   word, __ATOMIC_RELAXED, __HIP_MEMORY_SCOPE_AGENT);
            }
        }
        __syncthreads();  // B: drains h-publish (and long-done prefetch) before flag
        if (tid == 0)
            __hip_atomic_store(myflag, t + 1, __ATOMIC_RELAXED, __HIP_MEMORY_SCOPE_AGENT);
        xv = xn;
    }
}

// feats[b][t][tag] = h(b,t) . W_out[tag] + b_out[tag].  2048 blocks x 256, wave = one (b,t).
__global__ __launch_bounds__(256) void feats_k(const unsigned short* __restrict__ Hg,
                                               const float* __restrict__ W_out,
                                               const float* __restrict__ b_out,
                                               float* __restrict__ feats) {
    int wid = blockIdx.x * 4 + (threadIdx.x >> 6);
    int l = threadIdx.x & 63;
    int b = wid >> 9, t = wid & 511;
    uint2 hv = *(const uint2*)(Hg + (size_t)t * 4096 + (l >> 2) * 256 + b * 16 + (l & 3) * 4);
    float h0 = bf_lo(hv.x), h1 = bf_hi(hv.x), h2 = bf_lo(hv.y), h3 = bf_hi(hv.y);
    int ub = (l >> 2) * 16 + (l & 3) * 4;
#pragma unroll
    for (int tag = 0; tag < 6; tag++) {
        float4 w = *(const float4*)(W_out + tag * 256 + ub);
        float p = h0 * w.x + h1 * w.y + h2 * w.z + h3 * w.w;
#pragma unroll
        for (int off = 32; off; off >>= 1) p += __shfl_down(p, off);
        if (l == 0) feats[((size_t)b * 512 + t) * 6 + tag] = p + b_out[tag];
    }
}

// 16 blocks x 64 threads. Lane nx owns next-tag nx; fv broadcast via shfl each step.
__global__ __launch_bounds__(64) void crf_scan(const float* __restrict__ feats,
                                               const float* __restrict__ trans,
                                               float* __restrict__ out) {
    __shared__ float fl[T * 6];
    __shared__ unsigned char bp[T * 8];
    int b = blockIdx.x, tid = threadIdx.x;
    const float4* src = (const float4*)(feats + (size_t)b * 3072);
#pragma unroll
    for (int i = 0; i < 12; i++) ((float4*)fl)[tid + i * 64] = src[tid + i * 64];
    int nx = (tid < 6) ? tid : 0;
    float tr0 = trans[nx * 6 + 0], tr1 = trans[nx * 6 + 1], tr2 = trans[nx * 6 + 2],
          tr3 = trans[nx * 6 + 3], tr4 = trans[nx * 6 + 4], tr5 = trans[nx * 6 + 5];
    float fv0 = NEGV, fv1 = NEGV, fv2 = NEGV, fv3 = NEGV, fv4 = 0.f, fv5 = NEGV;  // START=4
    __syncthreads();
    for (int t = 0; t < T; t++) {
        float best = fv0 + tr0; int arg = 0; float s;
        s = fv1 + tr1; if (s > best) { best = s; arg = 1; }
        s = fv2 + tr2; if (s > best) { best = s; arg = 2; }
        s = fv3 + tr3; if (s > best) { best = s; arg = 3; }
        s = fv4 + tr4; if (s > best) { best = s; arg = 4; }
        s = fv5 + tr5; if (s > best) { best = s; arg = 5; }  // strict >: first-max
        float nf = best + fl[t * 6 + nx];
        if (tid < 6) bp[t * 8 + tid] = (unsigned char)arg;
        fv0 = __shfl(nf, 0); fv1 = __shfl(nf, 1); fv2 = __shfl(nf, 2);
        fv3 = __shfl(nf, 3); fv4 = __shfl(nf, 4); fv5 = __shfl(nf, 5);
    }
    __syncthreads();
    if (tid == 0) {
        float best = fv0 + trans[STOP * 6 + 0]; int arg = 0; float s;
        s = fv1 + trans[STOP * 6 + 1]; if (s > best) { best = s; arg = 1; }
        s = fv2 + trans[STOP * 6 + 2]; if (s > best) { best = s; arg = 2; }
        s = fv3 + trans[STOP * 6 + 3]; if (s > best) { best = s; arg = 3; }
        s = fv4 + trans[STOP * 6 + 4]; if (s > best) { best = s; arg = 4; }
        s = fv5 + trans[STOP * 6 + 5]; if (s > best) { best = s; arg = 5; }
        out[b] = best;
        int tag = arg;
        float* paths = out + 16 + (size_t)b * 512;
        for (int t = T - 1; t >= 0; t--) {
            paths[t] = (float)tag;
            tag = bp[t * 8 + tag];
        }
    }
}

extern "C" void kernel_launch(void* const* d_in, const int* in_sizes, int n_in,
                              void* d_out, int out_size, void* d_ws, size_t ws_size,
                              hipStream_t stream) {
    const int* sentence = (const int*)d_in[0];
    const float* embedding = (const float*)d_in[1];
    const float* W_ih = (const float*)d_in[2];
    const float* W_hh = (const float*)d_in[3];
    const float* b_ih = (const float*)d_in[4];
    const float* b_hh = (const float*)d_in[5];
    const float* W_out = (const float*)d_in[6];
    const float* b_out = (const float*)d_in[7];
    const float* trans = (const float*)d_in[8];
    float* out = (float*)d_out;
    char* ws = (char*)d_ws;

    unsigned short* Xpb = (unsigned short*)ws;               // 16 MB
    float* WihT = (float*)(ws + 16777216);                   // 1 MB
    unsigned short* Wf = (unsigned short*)(ws + 17825792);   // 512 KB
    float* feats = (float*)(ws + 18350080);                  // 192 KB
    unsigned short* Hg = (unsigned short*)(ws + 18874368);   // 4 MB
    int* flags = (int*)(ws + 24117248);                      // 2 KB

    hipLaunchKernelGGL(transpose_wih, dim3(1024), dim3(256), 0, stream, W_ih, WihT, flags);
    hipLaunchKernelGGL(input_proj, dim3(BATCH * T / 16), dim3(1024), 0, stream,
                       sentence, embedding, WihT, b_ih, b_hh, Xpb);
    hipLaunchKernelGGL(wf_prep, dim3(128), dim3(256), 0, stream, W_hh, Wf);
    hipLaunchKernelGGL(lstm_mfma, dim3(NBLK), dim3(256), 0, stream, Wf, Xpb, Hg, flags);
    hipLaunchKernelGGL(feats_k, dim3(2048), dim3(256), 0, stream, Hg, W_out, b_out, feats);
    hipLaunchKernelGGL(crf_scan, dim3(BATCH), dim3(64), 0, stream, feats, trans, out);
}